// Round 1
// baseline (2616.811 us; speedup 1.0000x reference)
//
#include <hip/hip_runtime.h>
#include <math.h>

#define TS 2048      // tokens (B*S)
#define HDIM 1024    // H
#define NHEADS 8
#define HD 128
#define NKVH 2
#define RDIM 64
#define NE 8
#define NI 1024
#define MAXROWS 4608 // 4096 + 8*64 padding capacity

// ------------------------------------------------------------------
// RMSNorm: out[t,d] = w[d] * in[t,d] * rsqrt(mean(in^2) + eps)
// ------------------------------------------------------------------
__global__ __launch_bounds__(256) void rmsnorm_kernel(const float* __restrict__ in,
    const float* __restrict__ w, float* __restrict__ out, int D)
{
    int t = blockIdx.x;
    const float* row = in + (long)t * D;
    __shared__ float red[256];
    float ss = 0.f;
    for (int d = threadIdx.x; d < D; d += 256) { float v = row[d]; ss += v * v; }
    red[threadIdx.x] = ss; __syncthreads();
    for (int s = 128; s > 0; s >>= 1) {
        if (threadIdx.x < s) red[threadIdx.x] += red[threadIdx.x + s];
        __syncthreads();
    }
    float rms = rsqrtf(red[0] / D + 1e-6f);
    for (int d = threadIdx.x; d < D; d += 256)
        out[(long)t * D + d] = w[d] * row[d] * rms;
}

// ------------------------------------------------------------------
// Fused qk-norm (over full row of D) + partial RoPE (first 64 of each 128-d head)
// in-place safe (row cached in LDS). t = position index (B=1).
// ------------------------------------------------------------------
__global__ __launch_bounds__(256) void qknorm_rope_kernel(const float* __restrict__ in,
    const float* __restrict__ w, float* __restrict__ out, int D)
{
    int t = blockIdx.x;
    __shared__ float row[1024];
    __shared__ float red[256];
    const float* rp = in + (long)t * D;
    float ss = 0.f;
    for (int d = threadIdx.x; d < D; d += 256) { float v = rp[d]; row[d] = v; ss += v * v; }
    red[threadIdx.x] = ss; __syncthreads();
    for (int s = 128; s > 0; s >>= 1) {
        if (threadIdx.x < s) red[threadIdx.x] += red[threadIdx.x + s];
        __syncthreads();
    }
    float rms = rsqrtf(red[0] / D + 1e-6f);
    for (int d = threadIdx.x; d < D; d += 256) {
        int hd = d & (HD - 1);
        float o;
        if (hd < RDIM) {
            int j = hd & 31;
            float ex = (float)(2 * j) / (float)RDIM;
            float invf = 1.0f / powf(1.0e6f, ex);
            float ang = (float)t * invf;
            float sn, cs; sincosf(ang, &sn, &cs);
            if (hd < 32) {
                float n1 = row[d] * w[d], n2 = row[d + 32] * w[d + 32];
                o = (n1 * cs - n2 * sn) * rms;
            } else {
                float n2 = row[d] * w[d], n1 = row[d - 32] * w[d - 32];
                o = (n2 * cs + n1 * sn) * rms;
            }
        } else {
            o = row[d] * w[d] * rms;
        }
        out[(long)t * D + d] = o;
    }
}

// ------------------------------------------------------------------
// Generic f32 tiled GEMM. C = alpha*A@B(^T) + R.  BM=BN=64, BK=16, 4x4 micro.
// blockIdx.z batches with byte^W element strides sA/sB/sC/sR.
// ------------------------------------------------------------------
template<bool TRANSB>
__global__ __launch_bounds__(256) void gemm_f32(
    const float* __restrict__ A, int lda, long sA,
    const float* __restrict__ B, int ldb, long sB,
    float* __restrict__ C, int ldc, long sC,
    const float* __restrict__ R, int ldr, long sR,
    int M, int N, int K, float alpha)
{
    int z = blockIdx.z;
    A += z * sA; B += z * sB; C += z * sC; if (R) R += z * sR;
    int m0 = blockIdx.y * 64, n0 = blockIdx.x * 64;
    __shared__ float As[16][65];
    __shared__ float Bs[16][65];
    int tid = threadIdx.x;
    int tx = tid & 15, ty = tid >> 4;
    float acc[4][4] = {};
    for (int k0 = 0; k0 < K; k0 += 16) {
        {
            int kk = tid & 15, m = tid >> 4;
            for (int p = 0; p < 4; ++p, m += 16) {
                int gm = m0 + m, gk = k0 + kk;
                As[kk][m] = (gm < M && gk < K) ? A[(long)gm * lda + gk] : 0.f;
            }
        }
        if (!TRANSB) {
            int n = tid & 63, kk = tid >> 6;
            for (int p = 0; p < 4; ++p, kk += 4) {
                int gn = n0 + n, gk = k0 + kk;
                Bs[kk][n] = (gn < N && gk < K) ? B[(long)gk * ldb + gn] : 0.f;
            }
        } else {
            int kk = tid & 15, n = tid >> 4;
            for (int p = 0; p < 4; ++p, n += 16) {
                int gn = n0 + n, gk = k0 + kk;
                Bs[kk][n] = (gn < N && gk < K) ? B[(long)gn * ldb + gk] : 0.f;
            }
        }
        __syncthreads();
        #pragma unroll
        for (int kk = 0; kk < 16; ++kk) {
            float a[4], b[4];
            #pragma unroll
            for (int i = 0; i < 4; ++i) a[i] = As[kk][ty * 4 + i];
            #pragma unroll
            for (int j = 0; j < 4; ++j) b[j] = Bs[kk][tx * 4 + j];
            #pragma unroll
            for (int i = 0; i < 4; ++i)
                #pragma unroll
                for (int j = 0; j < 4; ++j) acc[i][j] += a[i] * b[j];
        }
        __syncthreads();
    }
    for (int i = 0; i < 4; ++i) {
        int gm = m0 + ty * 4 + i; if (gm >= M) continue;
        for (int j = 0; j < 4; ++j) {
            int gn = n0 + tx * 4 + j; if (gn >= N) continue;
            float vv = acc[i][j] * alpha;
            if (R) vv += R[(long)gm * ldr + gn];
            C[(long)gm * ldc + gn] = vv;
        }
    }
}

// ------------------------------------------------------------------
// Causal row softmax in-place on a (4, S, S) score group.
// blockIdx.x = q row, blockIdx.y = head-in-group. valid keys = q+1, rest -> 0.
// ------------------------------------------------------------------
__global__ __launch_bounds__(256) void softmax_kernel(float* __restrict__ sc, int S)
{
    long base = ((long)blockIdx.y * S + blockIdx.x) * S;
    float* rowp = sc + base;
    int valid = blockIdx.x + 1;
    __shared__ float red[256];
    float mx = -1e30f;
    for (int i = threadIdx.x; i < valid; i += 256) mx = fmaxf(mx, rowp[i]);
    red[threadIdx.x] = mx; __syncthreads();
    for (int s = 128; s > 0; s >>= 1) {
        if (threadIdx.x < s) red[threadIdx.x] = fmaxf(red[threadIdx.x], red[threadIdx.x + s]);
        __syncthreads();
    }
    mx = red[0]; __syncthreads();
    float sum = 0.f;
    for (int i = threadIdx.x; i < valid; i += 256) sum += expf(rowp[i] - mx);
    red[threadIdx.x] = sum; __syncthreads();
    for (int s = 128; s > 0; s >>= 1) {
        if (threadIdx.x < s) red[threadIdx.x] += red[threadIdx.x + s];
        __syncthreads();
    }
    float inv = 1.f / red[0];
    for (int i = threadIdx.x; i < S; i += 256)
        rowp[i] = (i < valid) ? expf(rowp[i] - mx) * inv : 0.f;
}

// ------------------------------------------------------------------
// Router: logits = h2 @ Wr (1024x8), sigmoid, top-2 of (sc+bias),
// weights = normalized unbiased sc. Also counts per expert.
// ------------------------------------------------------------------
__global__ __launch_bounds__(256) void router_kernel(const float* __restrict__ h2,
    const float* __restrict__ Wr, const float* __restrict__ rbias,
    int* __restrict__ topi, float* __restrict__ wts, int* __restrict__ counts)
{
    int t = blockIdx.x;
    __shared__ float red[256 * 8];
    float acc[8] = {};
    for (int hh = threadIdx.x; hh < HDIM; hh += 256) {
        float tv = h2[(long)t * HDIM + hh];
        #pragma unroll
        for (int e = 0; e < 8; ++e) acc[e] += tv * Wr[hh * 8 + e];
    }
    #pragma unroll
    for (int e = 0; e < 8; ++e) red[threadIdx.x * 8 + e] = acc[e];
    __syncthreads();
    for (int s = 128; s > 0; s >>= 1) {
        if (threadIdx.x < s)
            for (int e = 0; e < 8; ++e) red[threadIdx.x * 8 + e] += red[(threadIdx.x + s) * 8 + e];
        __syncthreads();
    }
    if (threadIdx.x == 0) {
        float sc[8], sb[8];
        for (int e = 0; e < 8; ++e) { sc[e] = 1.f / (1.f + expf(-red[e])); sb[e] = sc[e] + rbias[e]; }
        int i0 = 0;
        for (int e = 1; e < 8; ++e) if (sb[e] > sb[i0]) i0 = e;
        int i1 = -1;
        for (int e = 0; e < 8; ++e) { if (e == i0) continue; if (i1 < 0 || sb[e] > sb[i1]) i1 = e; }
        float w0 = sc[i0], w1 = sc[i1], s = w0 + w1;
        topi[t * 2] = i0; topi[t * 2 + 1] = i1;
        wts[t * 2] = w0 / s; wts[t * 2 + 1] = w1 / s;
        atomicAdd(&counts[i0], 1); atomicAdd(&counts[i1], 1);
    }
}

__global__ void zero16_kernel(int* p) { int i = threadIdx.x; if (i < 16) p[i] = 0; }

__global__ void scan_kernel(const int* __restrict__ counts, int* __restrict__ pstart)
{
    if (threadIdx.x == 0 && blockIdx.x == 0) {
        int off = 0;
        for (int e = 0; e < 8; ++e) { pstart[e] = off; off += (counts[e] + 63) & ~63; }
    }
}

__global__ __launch_bounds__(256) void scatter_kernel(const int* __restrict__ topi,
    const float* __restrict__ wts, const int* __restrict__ pstart, int* __restrict__ fill,
    int* __restrict__ rowTok, int* __restrict__ posOf)
{
    int t = blockIdx.x * blockDim.x + threadIdx.x;
    if (t >= TS) return;
    for (int kidx = 0; kidx < 2; ++kidx) {
        int e = topi[t * 2 + kidx];
        int pos = pstart[e] + atomicAdd(&fill[e], 1);
        rowTok[pos] = t;
        posOf[t * 2 + kidx] = pos;
    }
}

// ------------------------------------------------------------------
// MoE stage A: act[row,i] = silu(t.Wg[e][:,i]) * (t.Wu[e][:,i]), gathered rows.
// Grid (16 n-blocks, 64 row-blocks, 8 experts); early-exit on device count.
// ------------------------------------------------------------------
__global__ __launch_bounds__(256) void moe_gu_kernel(const float* __restrict__ h2,
    const float* __restrict__ Wg, const float* __restrict__ Wu,
    const int* __restrict__ rowTok, const int* __restrict__ counts,
    const int* __restrict__ pstart, float* __restrict__ act)
{
    int e = blockIdx.z, rb = blockIdx.y;
    int cnt = counts[e];
    if (rb * 64 >= cnt) return;
    int seg = pstart[e];
    const float* Bg = Wg + (long)e * HDIM * NI;
    const float* Bu = Wu + (long)e * HDIM * NI;
    __shared__ float As[16][65], Gs[16][65], Us[16][65];
    __shared__ int toks[64];
    int tid = threadIdx.x;
    if (tid < 64) {
        int r = rb * 64 + tid;
        toks[tid] = (r < cnt) ? rowTok[seg + r] : 0;
    }
    __syncthreads();
    int n0 = blockIdx.x * 64;
    int tx = tid & 15, ty = tid >> 4;
    float ag[4][4] = {}, au[4][4] = {};
    for (int k0 = 0; k0 < HDIM; k0 += 16) {
        {
            int kk = tid & 15, m = tid >> 4;
            for (int p = 0; p < 4; ++p, m += 16)
                As[kk][m] = h2[(long)toks[m] * HDIM + k0 + kk];
        }
        {
            int n = tid & 63, kk = tid >> 6;
            for (int p = 0; p < 4; ++p, kk += 4) {
                Gs[kk][n] = Bg[(long)(k0 + kk) * NI + n0 + n];
                Us[kk][n] = Bu[(long)(k0 + kk) * NI + n0 + n];
            }
        }
        __syncthreads();
        #pragma unroll
        for (int kk = 0; kk < 16; ++kk) {
            float a[4], g[4], u[4];
            #pragma unroll
            for (int i = 0; i < 4; ++i) a[i] = As[kk][ty * 4 + i];
            #pragma unroll
            for (int j = 0; j < 4; ++j) { g[j] = Gs[kk][tx * 4 + j]; u[j] = Us[kk][tx * 4 + j]; }
            #pragma unroll
            for (int i = 0; i < 4; ++i)
                #pragma unroll
                for (int j = 0; j < 4; ++j) { ag[i][j] += a[i] * g[j]; au[i][j] += a[i] * u[j]; }
        }
        __syncthreads();
    }
    for (int i = 0; i < 4; ++i) {
        long row = (long)seg + rb * 64 + ty * 4 + i;
        for (int j = 0; j < 4; ++j) {
            float g = ag[i][j], u = au[i][j];
            float sg = g / (1.f + expf(-g));
            act[row * NI + n0 + tx * 4 + j] = sg * u;
        }
    }
}

// ------------------------------------------------------------------
// MoE stage B: ybuf[row,:] = act[row,:] @ Wd[e]   (weights applied in final)
// ------------------------------------------------------------------
__global__ __launch_bounds__(256) void moe_down_kernel(const float* __restrict__ act,
    const float* __restrict__ Wd, const int* __restrict__ counts,
    const int* __restrict__ pstart, float* __restrict__ ybuf)
{
    int e = blockIdx.z, rb = blockIdx.y;
    int cnt = counts[e];
    if (rb * 64 >= cnt) return;
    long rowbase = (long)pstart[e] + rb * 64;
    const float* A = act + rowbase * NI;
    const float* Bm = Wd + (long)e * NI * HDIM;
    int n0 = blockIdx.x * 64;
    __shared__ float As[16][65], Bs[16][65];
    int tid = threadIdx.x, tx = tid & 15, ty = tid >> 4;
    float acc[4][4] = {};
    for (int k0 = 0; k0 < NI; k0 += 16) {
        {
            int kk = tid & 15, m = tid >> 4;
            for (int p = 0; p < 4; ++p, m += 16)
                As[kk][m] = A[(long)m * NI + k0 + kk];
        }
        {
            int n = tid & 63, kk = tid >> 6;
            for (int p = 0; p < 4; ++p, kk += 4)
                Bs[kk][n] = Bm[(long)(k0 + kk) * HDIM + n0 + n];
        }
        __syncthreads();
        #pragma unroll
        for (int kk = 0; kk < 16; ++kk) {
            float a[4], b[4];
            #pragma unroll
            for (int i = 0; i < 4; ++i) a[i] = As[kk][ty * 4 + i];
            #pragma unroll
            for (int j = 0; j < 4; ++j) b[j] = Bs[kk][tx * 4 + j];
            #pragma unroll
            for (int i = 0; i < 4; ++i)
                #pragma unroll
                for (int j = 0; j < 4; ++j) acc[i][j] += a[i] * b[j];
        }
        __syncthreads();
    }
    for (int i = 0; i < 4; ++i) {
        long r = rowbase + ty * 4 + i;
        for (int j = 0; j < 4; ++j)
            ybuf[r * HDIM + n0 + tx * 4 + j] = acc[i][j];
    }
}

// ------------------------------------------------------------------
// out[t,:] = x1[t,:] + w0 * ybuf[pos0,:] + w1 * ybuf[pos1,:]
// ------------------------------------------------------------------
__global__ __launch_bounds__(256) void final_kernel(const float* __restrict__ x1,
    const float* __restrict__ ybuf, const float* __restrict__ wts,
    const int* __restrict__ posOf, float* __restrict__ out)
{
    int t = blockIdx.x;
    float w0 = wts[t * 2], w1 = wts[t * 2 + 1];
    long p0 = posOf[t * 2], p1 = posOf[t * 2 + 1];
    const float4* xa = (const float4*)(x1 + (long)t * HDIM);
    const float4* y0 = (const float4*)(ybuf + p0 * HDIM);
    const float4* y1 = (const float4*)(ybuf + p1 * HDIM);
    float4* o = (float4*)(out + (long)t * HDIM);
    int i = threadIdx.x;
    float4 a = xa[i], b = y0[i], c = y1[i];
    o[i] = make_float4(a.x + w0 * b.x + w1 * c.x, a.y + w0 * b.y + w1 * c.y,
                       a.z + w0 * b.z + w1 * c.z, a.w + w0 * b.w + w1 * c.w);
}

// ------------------------------------------------------------------
extern "C" void kernel_launch(void* const* d_in, const int* in_sizes, int n_in,
                              void* d_out, int out_size, void* d_ws, size_t ws_size,
                              hipStream_t stream)
{
    const float* x       = (const float*)d_in[0];
    const float* ln_in   = (const float*)d_in[1];
    const float* ln_post = (const float*)d_in[2];
    const float* qn_w    = (const float*)d_in[3];
    const float* kn_w    = (const float*)d_in[4];
    const float* Wq      = (const float*)d_in[5];
    const float* Wk      = (const float*)d_in[6];
    const float* Wv      = (const float*)d_in[7];
    const float* Wo      = (const float*)d_in[8];
    const float* Wr      = (const float*)d_in[9];
    const float* rbias   = (const float*)d_in[10];
    const float* Wg      = (const float*)d_in[11];
    const float* Wu      = (const float*)d_in[12];
    const float* Wd      = (const float*)d_in[13];
    float* out = (float*)d_out;

    char* p = (char*)d_ws;
    auto alloc = [&](size_t nbytes) { char* r = p; p += (nbytes + 255) & ~(size_t)255; return r; };
    float* h    = (float*)alloc((size_t)TS * HDIM * 4);
    float* qb   = (float*)alloc((size_t)TS * 1024 * 4);
    float* kb   = (float*)alloc((size_t)TS * 256 * 4);
    float* vb   = (float*)alloc((size_t)TS * 256 * 4);
    float* ob   = (float*)alloc((size_t)TS * 1024 * 4);
    float* x1   = (float*)alloc((size_t)TS * HDIM * 4);
    float* h2   = (float*)alloc((size_t)TS * HDIM * 4);
    float* sbuf = (float*)alloc((size_t)4 * TS * TS * 4);   // 4 heads of scores (64 MB)
    float* act  = (float*)alloc((size_t)MAXROWS * NI * 4);
    float* ybuf = (float*)alloc((size_t)MAXROWS * HDIM * 4);
    float* wts  = (float*)alloc((size_t)TS * 2 * 4);
    int* topi   = (int*)alloc((size_t)TS * 2 * 4);
    int* ibuf   = (int*)alloc(16 * 4);                      // counts[8], fill[8]
    int* pstart = (int*)alloc(8 * 4);
    int* rowTok = (int*)alloc((size_t)MAXROWS * 4);
    int* posOf  = (int*)alloc((size_t)TS * 2 * 4);

    zero16_kernel<<<1, 64, 0, stream>>>(ibuf);
    rmsnorm_kernel<<<TS, 256, 0, stream>>>(x, ln_in, h, HDIM);

    // QKV projections
    gemm_f32<false><<<dim3(1024 / 64, TS / 64, 1), 256, 0, stream>>>(
        h, HDIM, 0, Wq, 1024, 0, qb, 1024, 0, nullptr, 0, 0, TS, 1024, HDIM, 1.f);
    gemm_f32<false><<<dim3(256 / 64, TS / 64, 1), 256, 0, stream>>>(
        h, HDIM, 0, Wk, 256, 0, kb, 256, 0, nullptr, 0, 0, TS, 256, HDIM, 1.f);
    gemm_f32<false><<<dim3(256 / 64, TS / 64, 1), 256, 0, stream>>>(
        h, HDIM, 0, Wv, 256, 0, vb, 256, 0, nullptr, 0, 0, TS, 256, HDIM, 1.f);

    qknorm_rope_kernel<<<TS, 256, 0, stream>>>(qb, qn_w, qb, 1024);
    qknorm_rope_kernel<<<TS, 256, 0, stream>>>(kb, kn_w, kb, 256);

    // Attention per kv-group (4 heads each): scores -> causal softmax -> PV
    const float scal = 0.08838834764831845f; // 1/sqrt(128)
    for (int g = 0; g < 2; ++g) {
        gemm_f32<true><<<dim3(TS / 64, TS / 64, 4), 256, 0, stream>>>(
            qb + g * 512, 1024, 128, kb + g * 128, 256, 0, sbuf, TS, (long)TS * TS,
            nullptr, 0, 0, TS, TS, HD, scal);
        softmax_kernel<<<dim3(TS, 4), 256, 0, stream>>>(sbuf, TS);
        gemm_f32<false><<<dim3(HD / 64, TS / 64, 4), 256, 0, stream>>>(
            sbuf, TS, (long)TS * TS, vb + g * 128, 256, 0, ob + g * 512, 1024, 128,
            nullptr, 0, 0, TS, HD, TS, 1.f);
    }

    // x1 = x + o @ Wo
    gemm_f32<false><<<dim3(1024 / 64, TS / 64, 1), 256, 0, stream>>>(
        ob, 1024, 0, Wo, 1024, 0, x1, 1024, 0, x, 1024, 0, TS, 1024, 1024, 1.f);

    rmsnorm_kernel<<<TS, 256, 0, stream>>>(x1, ln_post, h2, HDIM);

    // Router + expert grouping
    router_kernel<<<TS, 256, 0, stream>>>(h2, Wr, rbias, topi, wts, ibuf);
    scan_kernel<<<1, 1, 0, stream>>>(ibuf, pstart);
    scatter_kernel<<<8, 256, 0, stream>>>(topi, wts, pstart, ibuf + 8, rowTok, posOf);

    // Sparse MoE
    moe_gu_kernel<<<dim3(NI / 64, 64, NE), 256, 0, stream>>>(h2, Wg, Wu, rowTok, ibuf, pstart, act);
    moe_down_kernel<<<dim3(HDIM / 64, 64, NE), 256, 0, stream>>>(act, Wd, ibuf, pstart, ybuf);

    final_kernel<<<TS, 256, 0, stream>>>(x1, ybuf, wts, posOf, out);
}

// Round 5
// 579.820 us; speedup vs baseline: 4.5131x; 4.5131x over previous
//
#include <hip/hip_runtime.h>
#include <math.h>

#define TS 2048
#define HDIM 1024
#define NHEADS 8
#define HD 128
#define NKVH 2
#define RDIM 64
#define NE 8
#define NI 1024
#define MAXROWS 5120   // 4096 + 8*128 pad capacity

typedef unsigned short u16;
typedef __attribute__((ext_vector_type(8))) short bf16x8;
typedef __attribute__((ext_vector_type(4))) float f32x4;

__device__ __forceinline__ u16 f2bf(float f) {
    union { float f; unsigned u; } v; v.f = f;
    unsigned r = v.u + 0x7fffu + ((v.u >> 16) & 1u);
    return (u16)(r >> 16);
}
__device__ __forceinline__ float bf2f(u16 h) {
    union { unsigned u; float f; } v; v.u = ((unsigned)h) << 16;
    return v.f;
}

__device__ __forceinline__ void gload16(const u16* g, u16* lds) {
    __builtin_amdgcn_global_load_lds(
        (const __attribute__((address_space(1))) unsigned int*)g,
        (__attribute__((address_space(3))) unsigned int*)lds,
        16, 0, 0);
}

// ------------------------------------------------------------------
// Transpose + f32->bf16:  out[C][R] = (bf16) in[R][C]
// ------------------------------------------------------------------
__global__ __launch_bounds__(256) void transp_kernel(const float* __restrict__ in,
    u16* __restrict__ out, int R, int C, long sIn, long sOut)
{
    in += (long)blockIdx.z * sIn; out += (long)blockIdx.z * sOut;
    __shared__ float t[32][33];
    int c0 = blockIdx.x * 32, r0 = blockIdx.y * 32;
    for (int i = threadIdx.y; i < 32; i += 8)
        t[i][threadIdx.x] = in[(long)(r0 + i) * C + c0 + threadIdx.x];
    __syncthreads();
    for (int i = threadIdx.y; i < 32; i += 8)
        out[(long)(c0 + i) * R + r0 + threadIdx.x] = f2bf(t[threadIdx.x][i]);
}

// ------------------------------------------------------------------
// RMSNorm f32 in -> bf16 out (+ optional f32 out)
// ------------------------------------------------------------------
__global__ __launch_bounds__(256) void rmsnorm_k(const float* __restrict__ in,
    const float* __restrict__ w, u16* __restrict__ outb, float* __restrict__ outf, int D)
{
    int t = blockIdx.x;
    const float* row = in + (long)t * D;
    __shared__ float red[256];
    float ss = 0.f;
    for (int d = threadIdx.x; d < D; d += 256) { float v = row[d]; ss += v * v; }
    red[threadIdx.x] = ss; __syncthreads();
    for (int s = 128; s > 0; s >>= 1) {
        if (threadIdx.x < s) red[threadIdx.x] += red[threadIdx.x + s];
        __syncthreads();
    }
    float rms = rsqrtf(red[0] / D + 1e-6f);
    for (int d = threadIdx.x; d < D; d += 256) {
        float v = w[d] * row[d] * rms;
        outb[(long)t * D + d] = f2bf(v);
        if (outf) outf[(long)t * D + d] = v;
    }
}

// ------------------------------------------------------------------
// In-place qk rmsnorm (full row D) + partial RoPE on bf16 buffer
// ------------------------------------------------------------------
__global__ __launch_bounds__(256) void qknorm_rope_bf(u16* __restrict__ q,
    const float* __restrict__ w, int D)
{
    int t = blockIdx.x;
    __shared__ float row[1024];
    __shared__ float red[256];
    u16* rp = q + (long)t * D;
    float ss = 0.f;
    for (int d = threadIdx.x; d < D; d += 256) { float v = bf2f(rp[d]); row[d] = v; ss += v * v; }
    red[threadIdx.x] = ss; __syncthreads();
    for (int s = 128; s > 0; s >>= 1) {
        if (threadIdx.x < s) red[threadIdx.x] += red[threadIdx.x + s];
        __syncthreads();
    }
    float rms = rsqrtf(red[0] / D + 1e-6f);
    for (int d = threadIdx.x; d < D; d += 256) {
        int hd = d & (HD - 1);
        float o;
        if (hd < RDIM) {
            int j = hd & 31;
            float ex = (float)(2 * j) / (float)RDIM;
            float invf = 1.0f / powf(1.0e6f, ex);
            float ang = (float)t * invf;
            float sn, cs; sincosf(ang, &sn, &cs);
            if (hd < 32) {
                float n1 = row[d] * w[d], n2 = row[d + 32] * w[d + 32];
                o = (n1 * cs - n2 * sn) * rms;
            } else {
                float n2 = row[d] * w[d], n1 = row[d - 32] * w[d - 32];
                o = (n2 * cs + n1 * sn) * rms;
            }
        } else {
            o = row[d] * w[d] * rms;
        }
        rp[d] = f2bf(o);
    }
}

// ------------------------------------------------------------------
// bf16 MFMA GEMM: C = alpha * A[M][K] @ Bt[N][K]^T (+R)
// 128x128 tile, BK=32, 4 waves (2x2 of 64x64), 16x16x32 MFMA.
// OBF: bf16 C. RES: +R f32. CSKIP: skip blocks above causal diag.
// CKLIM: K limited to m0+BM (causal PV). GQAB: B z-stride uses z>>2.
// MOE: expert segment lookup via pstart/cnts; B += z*sB + e*sA.
// ------------------------------------------------------------------
template<int OBF, int RES, int CSKIP, int CKLIM, int GQAB, int MOE>
__global__ __launch_bounds__(256) void gemm_k(
    const u16* __restrict__ A, int lda, long sA,
    const u16* __restrict__ Bt, int ldb, long sB,
    void* __restrict__ Cv, int ldc, long sC,
    const float* __restrict__ R, int ldr,
    const int* __restrict__ pstart, const int* __restrict__ cnts,
    int M, int N, int K, float alpha)
{
    int z = blockIdx.z;
    int m0 = blockIdx.y * 128, n0 = blockIdx.x * 128;
    if (CSKIP) { if (n0 > m0 + 127) return; }
    if (MOE) {
        int found = -1;
        for (int e = 0; e < NE; ++e) {
            int s = pstart[e], cpad = (cnts[e] + 127) & ~127;
            if (m0 >= s && m0 < s + cpad) { found = e; break; }
        }
        if (found < 0) return;
        Bt += (long)z * sB + (long)found * sA;
        Cv = (char*)Cv + (long)z * sC * (OBF ? 2 : 4);
    } else {
        A += (long)z * sA;
        Bt += (GQAB ? (long)(z >> 2) : (long)z) * sB;
        Cv = (char*)Cv + (long)z * sC * (OBF ? 2 : 4);
    }
    int Keff = K;
    if (CKLIM) Keff = min(K, m0 + 128);

    __shared__ u16 As[128 * 32];
    __shared__ u16 Bs[128 * 32];
    int tid = threadIdx.x, w = tid >> 6, l = tid & 63;
    int wm = w >> 1, wn = w & 1;
    int lane = l & 15, kg = l >> 4;
    f32x4 acc[4][4] = {};

    for (int k0 = 0; k0 < Keff; k0 += 32) {
        #pragma unroll
        for (int j = 0; j < 2; ++j) {
            int cu = j * 256 + w * 64;      // wave-uniform chunk base
            int c = cu + l;                 // per-lane chunk
            int row = c >> 2, slot = c & 3;
            gload16(A + (long)(m0 + row) * lda + k0 + slot * 8, As + cu * 8);
            gload16(Bt + (long)(n0 + row) * ldb + k0 + slot * 8, Bs + cu * 8);
        }
        __syncthreads();
        bf16x8 af[4], bfv[4];
        #pragma unroll
        for (int mf = 0; mf < 4; ++mf)
            af[mf] = *(const bf16x8*)&As[(wm * 64 + mf * 16 + lane) * 32 + kg * 8];
        #pragma unroll
        for (int nf = 0; nf < 4; ++nf)
            bfv[nf] = *(const bf16x8*)&Bs[(wn * 64 + nf * 16 + lane) * 32 + kg * 8];
        #pragma unroll
        for (int mf = 0; mf < 4; ++mf)
            #pragma unroll
            for (int nf = 0; nf < 4; ++nf)
                acc[mf][nf] = __builtin_amdgcn_mfma_f32_16x16x32_bf16(af[mf], bfv[nf], acc[mf][nf], 0, 0, 0);
        __syncthreads();
    }

    #pragma unroll
    for (int mf = 0; mf < 4; ++mf) {
        #pragma unroll
        for (int r = 0; r < 4; ++r) {
            int gm = m0 + wm * 64 + mf * 16 + kg * 4 + r;
            #pragma unroll
            for (int nf = 0; nf < 4; ++nf) {
                int gn = n0 + wn * 64 + nf * 16 + lane;
                float v = acc[mf][nf][r] * alpha;
                if (RES) v += R[(long)gm * ldr + gn];
                if (OBF) ((u16*)Cv)[(long)gm * ldc + gn] = f2bf(v);
                else     ((float*)Cv)[(long)gm * ldc + gn] = v;
            }
        }
    }
}

// ------------------------------------------------------------------
// Causal softmax on bf16 scores, in place; writes only up to the
// causal block boundary kmax = ((q>>7)+1)*128.
// ------------------------------------------------------------------
__global__ __launch_bounds__(256) void softmax_bf16(u16* __restrict__ sc, int S)
{
    int q = blockIdx.x;
    long base = ((long)blockIdx.y * S + q) * S;
    u16* row = sc + base;
    int valid = q + 1;
    int kmax = ((q >> 7) + 1) << 7;
    __shared__ float red[256];
    int i0 = threadIdx.x * 8;
    bf16x8 raw = *(const bf16x8*)&row[i0];
    float v[8];
    #pragma unroll
    for (int j = 0; j < 8; ++j) v[j] = bf2f((u16)raw[j]);
    float mx = -1e30f;
    #pragma unroll
    for (int j = 0; j < 8; ++j) if (i0 + j < valid) mx = fmaxf(mx, v[j]);
    red[threadIdx.x] = mx; __syncthreads();
    for (int s = 128; s > 0; s >>= 1) {
        if (threadIdx.x < s) red[threadIdx.x] = fmaxf(red[threadIdx.x], red[threadIdx.x + s]);
        __syncthreads();
    }
    mx = red[0]; __syncthreads();
    float e[8]; float sum = 0.f;
    #pragma unroll
    for (int j = 0; j < 8; ++j) { e[j] = (i0 + j < valid) ? expf(v[j] - mx) : 0.f; sum += e[j]; }
    red[threadIdx.x] = sum; __syncthreads();
    for (int s = 128; s > 0; s >>= 1) {
        if (threadIdx.x < s) red[threadIdx.x] += red[threadIdx.x + s];
        __syncthreads();
    }
    float inv = 1.f / red[0];
    if (i0 < kmax) {
        bf16x8 o;
        #pragma unroll
        for (int j = 0; j < 8; ++j) o[j] = (short)f2bf(e[j] * inv);
        *(bf16x8*)&row[i0] = o;
    }
}

// ------------------------------------------------------------------
// Router (f32 h2), top-2 of sigmoid+bias, normalized sigmoid weights
// ------------------------------------------------------------------
__global__ __launch_bounds__(256) void router_kernel(const float* __restrict__ h2,
    const float* __restrict__ Wr, const float* __restrict__ rbias,
    int* __restrict__ topi, float* __restrict__ wts, int* __restrict__ counts)
{
    int t = blockIdx.x;
    __shared__ float red[256 * 8];
    float acc[8] = {};
    for (int hh = threadIdx.x; hh < HDIM; hh += 256) {
        float tv = h2[(long)t * HDIM + hh];
        #pragma unroll
        for (int e = 0; e < 8; ++e) acc[e] += tv * Wr[hh * 8 + e];
    }
    #pragma unroll
    for (int e = 0; e < 8; ++e) red[threadIdx.x * 8 + e] = acc[e];
    __syncthreads();
    for (int s = 128; s > 0; s >>= 1) {
        if (threadIdx.x < s)
            for (int e = 0; e < 8; ++e) red[threadIdx.x * 8 + e] += red[(threadIdx.x + s) * 8 + e];
        __syncthreads();
    }
    if (threadIdx.x == 0) {
        float sc[8], sb[8];
        for (int e = 0; e < 8; ++e) { sc[e] = 1.f / (1.f + expf(-red[e])); sb[e] = sc[e] + rbias[e]; }
        int i0 = 0;
        for (int e = 1; e < 8; ++e) if (sb[e] > sb[i0]) i0 = e;
        int i1 = -1;
        for (int e = 0; e < 8; ++e) { if (e == i0) continue; if (i1 < 0 || sb[e] > sb[i1]) i1 = e; }
        float w0 = sc[i0], w1 = sc[i1], s = w0 + w1;
        topi[t * 2] = i0; topi[t * 2 + 1] = i1;
        wts[t * 2] = w0 / s; wts[t * 2 + 1] = w1 / s;
        atomicAdd(&counts[i0], 1); atomicAdd(&counts[i1], 1);
    }
}

__global__ void zero16_kernel(int* p) { int i = threadIdx.x; if (i < 16) p[i] = 0; }

__global__ void scan_kernel(const int* __restrict__ counts, int* __restrict__ pstart)
{
    if (threadIdx.x == 0 && blockIdx.x == 0) {
        int off = 0;
        for (int e = 0; e < 8; ++e) { pstart[e] = off; off += (counts[e] + 127) & ~127; }
    }
}

__global__ __launch_bounds__(256) void scatter_kernel(const int* __restrict__ topi,
    const int* __restrict__ pstart, int* __restrict__ fill,
    int* __restrict__ rowTok, int* __restrict__ posOf)
{
    int t = blockIdx.x * blockDim.x + threadIdx.x;
    if (t >= TS) return;
    for (int kidx = 0; kidx < 2; ++kidx) {
        int e = topi[t * 2 + kidx];
        int pos = pstart[e] + atomicAdd(&fill[e], 1);
        rowTok[pos] = t;
        posOf[t * 2 + kidx] = pos;
    }
}

// Gather h2(bf16) rows into padded expert-grouped buffer (pads zeroed)
__global__ __launch_bounds__(128) void gather_kernel(const u16* __restrict__ h2b,
    const int* __restrict__ rowTok, const int* __restrict__ pstart,
    const int* __restrict__ counts, u16* __restrict__ Agath)
{
    int row = blockIdx.x;
    int tok = -1;
    for (int e = 0; e < 8; ++e) {
        int s = pstart[e], cpad = (counts[e] + 127) & ~127;
        if (row >= s && row < s + cpad) { if (row - s < counts[e]) tok = rowTok[row]; break; }
    }
    uint4* dst = (uint4*)(Agath + (long)row * HDIM);
    int t = threadIdx.x;
    if (tok >= 0) dst[t] = ((const uint4*)(h2b + (long)tok * HDIM))[t];
    else dst[t] = make_uint4(0, 0, 0, 0);
}

// act = silu(g) * u  from gu f32 [row][2048] -> bf16 [row][1024]
__global__ __launch_bounds__(256) void silu_kernel(const float* __restrict__ gu,
    u16* __restrict__ act)
{
    long r = blockIdx.x;
    const float* g = gu + r * 2048;
    for (int j = threadIdx.x; j < 1024; j += 256) {
        float gv = g[j], uv = g[j + 1024];
        float s = gv / (1.f + expf(-gv));
        act[r * 1024 + j] = f2bf(s * uv);
    }
}

__global__ __launch_bounds__(256) void final_kernel(const float* __restrict__ x1,
    const float* __restrict__ ybuf, const float* __restrict__ wts,
    const int* __restrict__ posOf, float* __restrict__ out)
{
    int t = blockIdx.x;
    float w0 = wts[t * 2], w1 = wts[t * 2 + 1];
    long p0 = posOf[t * 2], p1 = posOf[t * 2 + 1];
    const float4* xa = (const float4*)(x1 + (long)t * HDIM);
    const float4* y0 = (const float4*)(ybuf + p0 * HDIM);
    const float4* y1 = (const float4*)(ybuf + p1 * HDIM);
    float4* o = (float4*)(out + (long)t * HDIM);
    int i = threadIdx.x;
    float4 a = xa[i], b = y0[i], c = y1[i];
    o[i] = make_float4(a.x + w0 * b.x + w1 * c.x, a.y + w0 * b.y + w1 * c.y,
                       a.z + w0 * b.z + w1 * c.z, a.w + w0 * b.w + w1 * c.w);
}

// ------------------------------------------------------------------
extern "C" void kernel_launch(void* const* d_in, const int* in_sizes, int n_in,
                              void* d_out, int out_size, void* d_ws, size_t ws_size,
                              hipStream_t stream)
{
    const float* x       = (const float*)d_in[0];
    const float* ln_in   = (const float*)d_in[1];
    const float* ln_post = (const float*)d_in[2];
    const float* qn_w    = (const float*)d_in[3];
    const float* kn_w    = (const float*)d_in[4];
    const float* Wq      = (const float*)d_in[5];
    const float* Wk      = (const float*)d_in[6];
    const float* Wv      = (const float*)d_in[7];
    const float* Wo      = (const float*)d_in[8];
    const float* Wr      = (const float*)d_in[9];
    const float* rbias   = (const float*)d_in[10];
    const float* Wg      = (const float*)d_in[11];
    const float* Wu      = (const float*)d_in[12];
    const float* Wd      = (const float*)d_in[13];
    float* out = (float*)d_out;

    char* p = (char*)d_ws;
    auto alloc = [&](size_t nbytes) { char* r = p; p += (nbytes + 255) & ~(size_t)255; return r; };
    const long M1 = 1024L * 1024;
    u16* WqT  = (u16*)alloc(M1 * 2);
    u16* WkT  = (u16*)alloc(256L * 1024 * 2);
    u16* WvT  = (u16*)alloc(256L * 1024 * 2);
    u16* WoT  = (u16*)alloc(M1 * 2);
    u16* WguT = (u16*)alloc(2 * 8 * M1 * 2);      // [which][e][1024][1024]
    u16* WdT  = (u16*)alloc(8 * M1 * 2);
    u16* h    = (u16*)alloc((size_t)TS * HDIM * 2);
    u16* qb   = (u16*)alloc((size_t)TS * 1024 * 2);
    u16* kb   = (u16*)alloc((size_t)TS * 256 * 2);
    u16* vT   = (u16*)alloc((size_t)256 * TS * 2);
    u16* ob   = (u16*)alloc((size_t)TS * 1024 * 2);
    float* x1  = (float*)alloc((size_t)TS * HDIM * 4);
    float* h2f = (float*)alloc((size_t)TS * HDIM * 4);
    u16* h2b  = (u16*)alloc((size_t)TS * HDIM * 2);
    u16* Agath = (u16*)alloc((size_t)MAXROWS * HDIM * 2);
    // union region: sbuf16 (64MB) then reused as gu/act/ybuf (70MB)
    char* uni = alloc((size_t)8 * TS * TS * 2 > (size_t)MAXROWS * (2048 * 4 + 1024 * 2 + 1024 * 4)
                      ? (size_t)8 * TS * TS * 2 : (size_t)MAXROWS * (2048 * 4 + 1024 * 2 + 1024 * 4));
    u16*   sbuf = (u16*)uni;
    float* gu   = (float*)uni;
    u16*   act  = (u16*)(uni + (size_t)MAXROWS * 2048 * 4);
    float* ybuf = (float*)(uni + (size_t)MAXROWS * 2048 * 4 + (size_t)MAXROWS * 1024 * 2);
    float* wts  = (float*)alloc((size_t)TS * 2 * 4);
    int* topi   = (int*)alloc((size_t)TS * 2 * 4);
    int* ibuf   = (int*)alloc(16 * 4);   // counts[8], fill[8]
    int* pstart = (int*)alloc(8 * 4);
    int* rowTok = (int*)alloc((size_t)MAXROWS * 4);
    int* posOf  = (int*)alloc((size_t)TS * 2 * 4);

    dim3 tb(32, 8);
    zero16_kernel<<<1, 64, 0, stream>>>(ibuf);
    // weight transpose + bf16 convert
    transp_kernel<<<dim3(32, 32, 1), tb, 0, stream>>>(Wq, WqT, 1024, 1024, 0, 0);
    transp_kernel<<<dim3(8, 32, 1), tb, 0, stream>>>(Wk, WkT, 1024, 256, 0, 0);
    transp_kernel<<<dim3(8, 32, 1), tb, 0, stream>>>(Wv, WvT, 1024, 256, 0, 0);
    transp_kernel<<<dim3(32, 32, 1), tb, 0, stream>>>(Wo, WoT, 1024, 1024, 0, 0);
    transp_kernel<<<dim3(32, 32, 8), tb, 0, stream>>>(Wg, WguT, 1024, 1024, M1, M1);
    transp_kernel<<<dim3(32, 32, 8), tb, 0, stream>>>(Wu, WguT + 8 * M1, 1024, 1024, M1, M1);
    transp_kernel<<<dim3(32, 32, 8), tb, 0, stream>>>(Wd, WdT, 1024, 1024, M1, M1);

    rmsnorm_k<<<TS, 256, 0, stream>>>(x, ln_in, h, nullptr, HDIM);

    // QKV projections (bf16 out)
    gemm_k<1,0,0,0,0,0><<<dim3(8, 16, 1), 256, 0, stream>>>(
        h, 1024, 0, WqT, 1024, 0, qb, 1024, 0, nullptr, 0, nullptr, nullptr, TS, 1024, 1024, 1.f);
    gemm_k<1,0,0,0,0,0><<<dim3(2, 16, 1), 256, 0, stream>>>(
        h, 1024, 0, WkT, 1024, 0, kb, 256, 0, nullptr, 0, nullptr, nullptr, TS, 256, 1024, 1.f);
    // vT[n][t] = sum_k Wv[k][n] h[t][k]
    gemm_k<1,0,0,0,0,0><<<dim3(16, 2, 1), 256, 0, stream>>>(
        WvT, 1024, 0, h, 1024, 0, vT, TS, 0, nullptr, 0, nullptr, nullptr, 256, TS, 1024, 1.f);

    qknorm_rope_bf<<<TS, 256, 0, stream>>>(qb, qn_w, 1024);
    qknorm_rope_bf<<<TS, 256, 0, stream>>>(kb, kn_w, 256);

    // scores (causal block-skip, scale fused, bf16 out)
    gemm_k<1,0,1,0,1,0><<<dim3(16, 16, 8), 256, 0, stream>>>(
        qb, 1024, 128, kb, 256, 128, sbuf, TS, (long)TS * TS, nullptr, 0, nullptr, nullptr,
        TS, TS, HD, 0.08838834764831845f);
    softmax_bf16<<<dim3(TS, 8), 256, 0, stream>>>(sbuf, TS);
    // PV (causal K-limit)
    gemm_k<1,0,0,1,1,0><<<dim3(1, 16, 8), 256, 0, stream>>>(
        sbuf, TS, (long)TS * TS, vT, TS, (long)128 * TS, ob, 1024, 128, nullptr, 0, nullptr, nullptr,
        TS, HD, TS, 1.f);
    // x1 = ob @ Wo + x  (f32 out)
    gemm_k<0,1,0,0,0,0><<<dim3(8, 16, 1), 256, 0, stream>>>(
        ob, 1024, 0, WoT, 1024, 0, x1, 1024, 0, x, 1024, nullptr, nullptr, TS, 1024, 1024, 1.f);

    rmsnorm_k<<<TS, 256, 0, stream>>>(x1, ln_post, h2b, h2f, HDIM);

    router_kernel<<<TS, 256, 0, stream>>>(h2f, Wr, rbias, topi, wts, ibuf);
    scan_kernel<<<1, 1, 0, stream>>>(ibuf, pstart);
    scatter_kernel<<<8, 256, 0, stream>>>(topi, pstart, ibuf + 8, rowTok, posOf);
    gather_kernel<<<MAXROWS, 128, 0, stream>>>(h2b, rowTok, pstart, ibuf, Agath);

    // MoE gate+up: z=0 -> g, z=1 -> u ; gu[row][z*1024 + i]
    gemm_k<0,0,0,0,0,1><<<dim3(8, MAXROWS / 128, 2), 256, 0, stream>>>(
        Agath, 1024, M1, WguT, 1024, (long)8 * M1, gu, 2048, 1024, nullptr, 0, pstart, ibuf,
        MAXROWS, 1024, 1024, 1.f);
    silu_kernel<<<MAXROWS, 256, 0, stream>>>(gu, act);
    // MoE down
    gemm_k<0,0,0,0,0,1><<<dim3(8, MAXROWS / 128, 1), 256, 0, stream>>>(
        act, 1024, M1, WdT, 1024, 0, ybuf, 1024, 0, nullptr, 0, pstart, ibuf,
        MAXROWS, 1024, 1024, 1.f);

    final_kernel<<<TS, 256, 0, stream>>>(x1, ybuf, wts, posOf, out);
}